// Round 9
// baseline (191.871 us; speedup 1.0000x reference)
//
#include <hip/hip_runtime.h>
#include <math.h>

#define BATCH 4096
#define SEQ_T 512
#define ISZ   4
#define HID   64
#define OSZ   40
#define RPB   16     // batch rows per block (MFMA N); grid = 256 = 1 block/CU

typedef __attribute__((ext_vector_type(8))) _Float16     half8;
typedef __attribute__((ext_vector_type(2))) _Float16     half2v;
typedef __attribute__((ext_vector_type(4))) float        float4v;
typedef __attribute__((ext_vector_type(2))) unsigned int uint2v;

static __device__ __forceinline__ half2v pk_f16(float a, float b) {
    return __builtin_bit_cast(half2v, __builtin_amdgcn_cvt_pkrtz(a, b)); // v_cvt_pkrtz_f16_f32
}

// tanh from PRE-SCALED s = 2*log2e*z (scale folded into all weights):
// tanh(z) = 1 - 2*rcp(exp2(s)+1). Saturating, NaN-free. One less dep vs r8.
static __device__ __forceinline__ float fast_tanh_s(float s) {
    float e = __builtin_amdgcn_exp2f(s);
    return fmaf(-2.0f, __builtin_amdgcn_rcpf(e + 1.0f), 1.0f);
}

// LDS-only barrier: ds_writes drained (lgkmcnt), global x prefetches stay in flight.
#define LDS_BARRIER() asm volatile("s_waitcnt lgkmcnt(0)\n\ts_barrier" ::: "memory")

// r8 base (127.7us): phase-split (grp0 even / grp1 odd updates), h stored as
// plain f16, W 2-term compensated split, 4-deep named-reg x pipeline.
// r9 (chain shave, math-identical): (1) 2*log2e folded into W_hh/W_ih/bias so
// the MFMA output feeds exp2 directly (kills the v_mul dep); (2) MFMA depth
// 2->1: 4 independent MFMAs + 2-level f32 join (1 MFMA dep + ~20cy adds vs
// 2 MFMA deps); (3) setprio(1) on the ACTIVE chain (active/shadow role split
// per SIMD = T5's prerequisite exists here).
__global__ __launch_bounds__(512, 1)
void rnn_f16x2_kernel(const float* __restrict__ x,
                      const float* __restrict__ W_ih,
                      const float* __restrict__ W_hh,
                      const float* __restrict__ b_ih,
                      const float* __restrict__ b_hh,
                      const float* __restrict__ fc_W,
                      const float* __restrict__ fc_b,
                      float* __restrict__ out)
{
    // hterm[buf][g][n][j] = h[k=8g+j] (f16) for batch col n (B-fragment-native).
    // Reader lane(n,q): b128 at [q][n][0] / [4+q][n][0] -> 2-way alias (free).
    // Writer lane(n,q) wave wg: g=2wg+(q>>1), j0=4(q&1): one b64, 2-way (free).
    __shared__ __attribute__((aligned(16))) _Float16 hterm[2][8][16][8];
    __shared__ __attribute__((aligned(16))) float hf[16][68];

    const int tid  = threadIdx.x;
    const int grp  = tid >> 8;         // 0: even updates, 1: odd updates
    const int wg   = (tid >> 6) & 3;   // wave-in-group: M-slice of H
    const int lane = tid & 63;
    const int n    = lane & 15;        // A: row m; B/C/D: batch col n
    const int q    = lane >> 4;
    const int blk0 = blockIdx.x * RPB;
    const float SC = 2.885390081777927f;  // 2*log2(e)

    // h(0) = 0: zero both buffers
    {
        unsigned int* p = (unsigned int*)hterm;
        #pragma unroll
        for (int i = tid; i < (int)(sizeof(hterm) / 4); i += 512) p[i] = 0u;
    }

    // ---- static A fragments: SC * W_hh row 16wg+n, 2-term f16 split, chunks c=0,1 ----
    half8 A10, A11, A20, A21;   // A1x = hi term, A2x = residual term
    {
        const float* wr = W_hh + (16 * wg + n) * HID;
        #pragma unroll
        for (int j = 0; j < 8; ++j) {
            float f0 = SC * wr[     8 * q + j];
            float f1 = SC * wr[32 + 8 * q + j];
            _Float16 h0 = (_Float16)f0; A10[j] = h0; A20[j] = (_Float16)(f0 - (float)h0);
            _Float16 h1 = (_Float16)f1; A11[j] = h1; A21[j] = (_Float16)(f1 - (float)h1);
        }
    }

    // ---- SC-scaled fp32 x-projection weights + bias for C rows 16wg + 4q + r ----
    const int r0 = 16 * wg + 4 * q;
    float wih[4][4], bias[4];
    #pragma unroll
    for (int r = 0; r < 4; ++r) {
        bias[r] = SC * (b_ih[r0 + r] + b_hh[r0 + r]);
        #pragma unroll
        for (int i = 0; i < ISZ; ++i) wih[r][i] = SC * W_ih[(r0 + r) * ISZ + i];
    }

    // ---- 4-deep named x pipeline: this group's updates are u = grp, grp+2, ... ----
    const float* xrow = x + (size_t)(blk0 + n) * SEQ_T * ISZ;
    float4v xa = *(const float4v*)(xrow + (size_t)(grp    ) * ISZ);
    float4v xb = *(const float4v*)(xrow + (size_t)(grp + 2) * ISZ);
    float4v xc = *(const float4v*)(xrow + (size_t)(grp + 4) * ISZ);
    float4v xd = *(const float4v*)(xrow + (size_t)(grp + 6) * ISZ);
    int tnext = grp + 8;

    const int gw = 2 * wg + (q >> 1);
    const int j0 = 4 * (q & 1);

    float p0, p1, p2, p3;
    float hl0 = 0.f, hl1 = 0.f, hl2 = 0.f, hl3 = 0.f;

    __syncthreads();   // zero-init visible (prologue: full drain fine)

#define MFMA16(A, B, C) __builtin_amdgcn_mfma_f32_16x16x32_f16((A), (B), (C), 0, 0, 0)

// Consume XR (xp projection, SC-scaled), then reload the SAME register in
// place for use 4 phase-pairs later (r6 pattern).
#define XP_FROM(XR)                                                            \
    {                                                                          \
        p0 = bias[0]; p1 = bias[1]; p2 = bias[2]; p3 = bias[3];                \
        _Pragma("unroll")                                                      \
        for (int i = 0; i < ISZ; ++i) {                                        \
            p0 = fmaf(XR[i], wih[0][i], p0);                                   \
            p1 = fmaf(XR[i], wih[1][i], p1);                                   \
            p2 = fmaf(XR[i], wih[2][i], p2);                                   \
            p3 = fmaf(XR[i], wih[3][i], p3);                                   \
        }                                                                      \
    }

#define XRELOAD(XR)                                                            \
    {                                                                          \
        int tn = tnext; if (tn > SEQ_T - 1) tn = SEQ_T - 1;                    \
        XR = *(const float4v*)(xrow + (size_t)tn * ISZ);                       \
        tnext += 2;                                                            \
    }

// 4 independent depth-1 MFMAs + 2-level f32 join; MFMA output is pre-scaled
// by SC so it feeds exp2 directly.
#define ACTIVE_STEP(RB, WB)                                                    \
    {                                                                          \
        __builtin_amdgcn_s_setprio(1);                                         \
        half8 B10 = *(const half8*)&hterm[RB][    q][n][0];                    \
        half8 B11 = *(const half8*)&hterm[RB][4 + q][n][0];                    \
        const float4v zz = {0.f, 0.f, 0.f, 0.f};                               \
        float4v cx = {p0, p1, p2, p3};                                         \
        float4v aA = MFMA16(A10, B10, cx);                                     \
        float4v aB = MFMA16(A11, B11, zz);                                     \
        float4v aC = MFMA16(A20, B10, zz);                                     \
        float4v aD = MFMA16(A21, B11, zz);                                     \
        float4v sj = (aA + aB) + (aC + aD);                                    \
        hl0 = fast_tanh_s(sj[0]); hl1 = fast_tanh_s(sj[1]);                    \
        hl2 = fast_tanh_s(sj[2]); hl3 = fast_tanh_s(sj[3]);                    \
        half2v hi01 = pk_f16(hl0, hl1), hi23 = pk_f16(hl2, hl3);               \
        uint2v whi = { __builtin_bit_cast(unsigned int, hi01),                 \
                       __builtin_bit_cast(unsigned int, hi23) };               \
        *(uint2v*)&hterm[WB][gw][n][j0] = whi;                                 \
        __builtin_amdgcn_s_setprio(0);                                         \
    }

    if (grp == 0) {
        // even updates: active in phase A, xp-precompute in phase B (idle)
        XP_FROM(xa); XRELOAD(xa);                // xp for update 0
        for (int it = 0; it < SEQ_T / 2; it += 4) {
            ACTIVE_STEP(0, 1); LDS_BARRIER(); XP_FROM(xb); XRELOAD(xb); LDS_BARRIER();
            ACTIVE_STEP(0, 1); LDS_BARRIER(); XP_FROM(xc); XRELOAD(xc); LDS_BARRIER();
            ACTIVE_STEP(0, 1); LDS_BARRIER(); XP_FROM(xd); XRELOAD(xd); LDS_BARRIER();
            ACTIVE_STEP(0, 1); LDS_BARRIER(); XP_FROM(xa); XRELOAD(xa); LDS_BARRIER();
        }
    } else {
        // odd updates: xp-precompute in phase A (idle), active in phase B
        for (int it = 0; it < SEQ_T / 2; it += 4) {
            XP_FROM(xa); XRELOAD(xa); LDS_BARRIER(); ACTIVE_STEP(1, 0); LDS_BARRIER();
            XP_FROM(xb); XRELOAD(xb); LDS_BARRIER(); ACTIVE_STEP(1, 0); LDS_BARRIER();
            XP_FROM(xc); XRELOAD(xc); LDS_BARRIER(); ACTIVE_STEP(1, 0); LDS_BARRIER();
            XP_FROM(xd); XRELOAD(xd); LDS_BARRIER(); ACTIVE_STEP(1, 0); LDS_BARRIER();
        }
    }
#undef ACTIVE_STEP
#undef XRELOAD
#undef XP_FROM
#undef MFMA16

    // ---- fc epilogue: final h (update 511) lives in group 1's registers ----
    if (grp == 1) {
        float4v hv = {hl0, hl1, hl2, hl3};
        *(float4v*)&hf[n][r0] = hv;
    }
    __syncthreads();
    for (int it = tid; it < RPB * OSZ; it += 512) {
        const int b = it / OSZ;
        const int o = it - b * OSZ;
        const float* wo = fc_W + o * HID;
        float acc = fc_b[o];
        #pragma unroll
        for (int j = 0; j < HID; ++j)
            acc = fmaf(hf[b][j], wo[j], acc);
        out[(size_t)(blk0 + b) * OSZ + o] = acc;
    }
}

extern "C" void kernel_launch(void* const* d_in, const int* in_sizes, int n_in,
                              void* d_out, int out_size, void* d_ws, size_t ws_size,
                              hipStream_t stream) {
    const float* x    = (const float*)d_in[0];
    const float* W_ih = (const float*)d_in[1];
    const float* W_hh = (const float*)d_in[2];
    const float* b_ih = (const float*)d_in[3];
    const float* b_hh = (const float*)d_in[4];
    const float* fc_W = (const float*)d_in[5];
    const float* fc_b = (const float*)d_in[6];
    float* out = (float*)d_out;

    rnn_f16x2_kernel<<<BATCH / RPB, 512, 0, stream>>>(
        x, W_ih, W_hh, b_ih, b_hh, fc_W, fc_b, out);
}